// Round 7
// baseline (873.600 us; speedup 1.0000x reference)
//
#include <hip/hip_runtime.h>
#include <stdint.h>

#define Bn 64
#define Sn 512
#define Hn 1024
#define En 768
#define Cn (Hn + En)   // 1792

typedef __bf16 bf16_t;
typedef bf16_t bf16x8 __attribute__((ext_vector_type(8)));
typedef float  f32x4  __attribute__((ext_vector_type(4)));
typedef unsigned int uint32;
typedef uint32 u32x4 __attribute__((ext_vector_type(4)));
typedef unsigned short ushort_t;

// flat element offsets of the bf16 scratch segments (order: text, aspect, w_text, w_aspect)
#define T_TEXT   33554432u   // 64*512*1024
#define T_ASPECT 58720256u   // + 64*512*768
#define T_WTEXT  125829120u  // + 64*1024*1024
#define T_TOTAL  163577856u  // + 64*768*768
#define WS_BF_BYTES ((size_t)T_TOTAL * 2)

// fp32 -> bf16 (round-half-up), pack two into one dword
__device__ __forceinline__ uint32 pack2_bf16(float a, float b) {
    uint32 ua = __float_as_uint(a) + 0x8000u;
    uint32 ub = __float_as_uint(b) + 0x8000u;
    return (ub & 0xFFFF0000u) | (ua >> 16);
}

// one streaming pass: all 4 fp32 tensors -> bf16 in d_ws (segment bounds are 8-aligned)
// R6: grid-stride with 2048 blocks (Guideline 11) instead of 79872 tiny blocks.
__global__ __launch_bounds__(256)
void convert_kernel(const float* __restrict__ text, const float* __restrict__ aspect,
                    const float* __restrict__ w_text, const float* __restrict__ w_aspect,
                    ushort_t* __restrict__ dst)
{
    const size_t stride = (size_t)gridDim.x * 256 * 8;
    for (size_t i = ((size_t)blockIdx.x * 256 + threadIdx.x) * 8; i < T_TOTAL; i += stride) {
        const float* src; size_t off;
        if (i < T_TEXT)        { src = text;     off = i; }
        else if (i < T_ASPECT) { src = aspect;   off = i - T_TEXT; }
        else if (i < T_WTEXT)  { src = w_text;   off = i - T_ASPECT; }
        else                   { src = w_aspect; off = i - T_WTEXT; }
        f32x4 a = *(const f32x4*)(src + off);
        f32x4 c = *(const f32x4*)(src + off + 4);
        u32x4 p = { pack2_bf16(a.x, a.y), pack2_bf16(a.z, a.w),
                    pack2_bf16(c.x, c.y), pack2_bf16(c.z, c.w) };
        *(u32x4*)(dst + i) = p;
    }
}

// ---------------------------------------------------------------------------
// scores[b,s] = sum_c w_combine[b,c] * tanh( (W @ X^T)[c,s] )
// 256x256 tile, 8 waves (2Mx4N), BK=64, 4 fat phases per iter (2 K-tiles).
// R5 counters (8-phase): MfmaUtil 16%, 23k cyc/iter = 3.5x m201's per-iter cost.
// Diagnosis: per-phase sync overhead (16 barriers/iter, 8-wave lockstep,
// 1 block/CU) + 96 ds_read_b128/lane/iter. Fix: one phase per (slot, A-half)
// computing BOTH LQ quadrants (32 MFMA), sharing B-fragments across quadrants:
// barriers 16->8/iter, reads 96->64/lane/iter.
//
// Phase plan per iter it (slot0 holds kt=2it, slot1 holds kt=2it+1):
//   Q1: slot0 HQ0 (reads A0h0 + B0 both)   stage A1h1,B1h0,B1h1 <- kt1
//   Q2: slot0 HQ1 (reads A0h1 + B0 both)   stage A0h0 <- kt2 (nl)   TAIL vmcnt(2)/(0)
//   Q3: slot1 HQ0 (reads A1h0 + B1 both)   stage A0h1,B0h0,B0h1 <- kt2 (nl)
//   Q4: slot1 HQ1 (reads A1h1 + B1 both)   stage A1h0 <- kt3 (nl)   TAIL vmcnt(2) (nl)
// Write-after-read (barrier-separated, audited): every staged half's last
// reader completed (lgkmcnt(0) before MFMA) >= one barrier before the stage.
// Counted waits: end-Q2 vmcnt(2) forces prevQ4's 2 + Q1's 6 (slot1 complete,
// cross-wave via the post-TAIL barrier) allowing Q2's pair in flight; end-Q4
// vmcnt(2) forces Q2's 2 + Q3's 6 (slot0 complete) allowing Q4's pair.
// Last iter: Q2 drains vmcnt(0); Q3/Q4 stage nothing -> LDS quiescent for the
// epilogue overlay.
// ---------------------------------------------------------------------------

#define STAGE_A(SLOT, H, KT) do {                                                       \
    const ushort_t* _g = Ag + (size_t)((H) * 128) * K + (size_t)(KT) * 64;              \
    __builtin_amdgcn_global_load_lds(                                                   \
        (const __attribute__((address_space(1))) void*)_g,                              \
        (__attribute__((address_space(3))) void*)&As[SLOT][(H) * 128 + wid * 8][0],     \
        16, 0, 0);                                                                      \
    __builtin_amdgcn_global_load_lds(                                                   \
        (const __attribute__((address_space(1))) void*)(_g + (size_t)64 * K),           \
        (__attribute__((address_space(3))) void*)&As[SLOT][(H) * 128 + 64 + wid * 8][0],\
        16, 0, 0);                                                                      \
} while (0)

#define STAGE_B(SLOT, H, KT) do {                                                       \
    const ushort_t* _g = Bg + (size_t)((H) * 128) * K + (size_t)(KT) * 64;              \
    __builtin_amdgcn_global_load_lds(                                                   \
        (const __attribute__((address_space(1))) void*)_g,                              \
        (__attribute__((address_space(3))) void*)&Bs[SLOT][(H) * 128 + wid * 8][0],     \
        16, 0, 0);                                                                      \
    __builtin_amdgcn_global_load_lds(                                                   \
        (const __attribute__((address_space(1))) void*)(_g + (size_t)64 * K),           \
        (__attribute__((address_space(3))) void*)&Bs[SLOT][(H) * 128 + 64 + wid * 8][0],\
        16, 0, 0);                                                                      \
} while (0)

#define TAIL_NONE
#define TAIL_V2L if (nl) { asm volatile("s_waitcnt vmcnt(2)" ::: "memory"); }           \
                 else    { asm volatile("s_waitcnt vmcnt(0)" ::: "memory"); }
#define TAIL_V2N if (nl) { asm volatile("s_waitcnt vmcnt(2)" ::: "memory"); }

// fat phase: 16 ds_read_b128 (A-half HQ + B both quadrants) + stages | barrier |
// lgkm0 | 32 MFMA (both LQ) | TAIL | barrier
#define PHASE4(SLOT, HQ, TAIL, ...) do {                                                \
    bf16x8 af[2][4], bv[2][2][2];                                                       \
    _Pragma("unroll")                                                                   \
    for (int ks = 0; ks < 2; ++ks) {                                                    \
        const int cc = ks ? c1 : c0;                                                    \
        _Pragma("unroll")                                                               \
        for (int mi = 0; mi < 4; ++mi)                                                  \
            af[ks][mi] = *(const bf16x8*)&As[SLOT][(HQ) * 128 + rowA0 + mi * 16][cc];   \
        _Pragma("unroll")                                                               \
        for (int lq = 0; lq < 2; ++lq)                                                  \
            _Pragma("unroll")                                                           \
            for (int nj = 0; nj < 2; ++nj)                                              \
                bv[lq][ks][nj] = *(const bf16x8*)&Bs[SLOT][lq * 128 + rowB0 + nj * 16][cc]; \
    }                                                                                   \
    __VA_ARGS__;                                                                        \
    __builtin_amdgcn_sched_barrier(0);                                                  \
    __builtin_amdgcn_s_barrier();                                                       \
    asm volatile("s_waitcnt lgkmcnt(0)" ::: "memory");                                  \
    __builtin_amdgcn_sched_barrier(0);                                                  \
    __builtin_amdgcn_s_setprio(1);                                                      \
    _Pragma("unroll")                                                                   \
    for (int ks = 0; ks < 2; ++ks)                                                      \
        _Pragma("unroll")                                                               \
        for (int lq = 0; lq < 2; ++lq)                                                  \
            _Pragma("unroll")                                                           \
            for (int mi = 0; mi < 4; ++mi)                                              \
                _Pragma("unroll")                                                       \
                for (int nj = 0; nj < 2; ++nj)                                          \
                    acc[HQ][lq][mi][nj] = __builtin_amdgcn_mfma_f32_16x16x32_bf16(      \
                        af[ks][mi], bv[lq][ks][nj], acc[HQ][lq][mi][nj], 0, 0, 0);      \
    __builtin_amdgcn_s_setprio(0);                                                      \
    TAIL                                                                                \
    __builtin_amdgcn_sched_barrier(0);                                                  \
    __builtin_amdgcn_s_barrier();                                                       \
} while (0)

__global__ __launch_bounds__(512, 2)
void scores_kernel(const ushort_t* __restrict__ text_bf,
                   const ushort_t* __restrict__ aspect_bf,
                   const ushort_t* __restrict__ wtext_bf,
                   const ushort_t* __restrict__ waspect_bf,
                   const float* __restrict__ w_combine,
                   float* __restrict__ scores)
{
    // LDS: 2 K-tile slots x [256 rows][64 cols] bf16 per matrix = 128 KiB total.
    // Row r's 8-element chunks stored at chunk c = global_chunk ^ (r&7) (bank-even b128).
    __shared__ __align__(16) ushort_t As[2][256][64];
    __shared__ __align__(16) ushort_t Bs[2][256][64];

    // bijective XCD swizzle: 896 = 8 XCD * 112; each XCD gets 8 contiguous batches
    const int lin = blockIdx.x + 2 * (blockIdx.y + 7 * blockIdx.z);
    const int wg  = (lin & 7) * 112 + (lin >> 3);
    const int bx = wg % 2;
    const int by = (wg / 2) % 7;
    const int b  = wg / 14;

    const int m0 = by * 256;            // channel tile base (0..1536)
    const int n0 = bx * 256;            // s tile base (0 or 256)
    const bool is_text = (m0 < Hn);
    const int K  = is_text ? Hn : En;   // 1024 or 768
    const int NI = K >> 7;              // iters (2 K-tiles of 64 per iter): 8 or 6
    const ushort_t* Amat = is_text ? (wtext_bf   + (size_t)b * Hn * Hn + (size_t)m0 * Hn)
                                   : (waspect_bf + (size_t)b * En * En + (size_t)(m0 - Hn) * En);
    const ushort_t* Bmat = is_text ? (text_bf   + (size_t)b * Sn * Hn + (size_t)n0 * Hn)
                                   : (aspect_bf + (size_t)b * Sn * En + (size_t)n0 * En);

    const int t = threadIdx.x;
    const int wid = t >> 6, lane = t & 63;
    const int r16 = lane & 15, q4 = lane >> 4;
    const int wr = wid >> 2, wc = wid & 3;       // wave grid 2(M) x 4(N)
    const int rowA0 = wr * 64 + r16;             // + HQ*128 + mi*16
    const int rowB0 = wc * 32 + r16;             // + LQ*128 + nj*16
    const int c0 = ((0 + q4) ^ (r16 & 7)) * 8;   // swizzled chunk col, ks=0 (elements)
    const int c1 = ((4 + q4) ^ (r16 & 7)) * 8;   // ks=1

    // staging: thread t covers sub-row t>>3 (of 64) / chunk t&7; global chunk pre-swizzled
    const int srow = t >> 3;
    const int cg = (t & 7) ^ (srow & 7);
    const ushort_t* Ag = Amat + (size_t)srow * K + (size_t)cg * 8;
    const ushort_t* Bg = Bmat + (size_t)srow * K + (size_t)cg * 8;

    f32x4 acc[2][2][4][2];   // [A-half][B-half][mi][nj]
    #pragma unroll
    for (int a0 = 0; a0 < 2; ++a0)
        #pragma unroll
        for (int a1 = 0; a1 < 2; ++a1)
            #pragma unroll
            for (int a2 = 0; a2 < 4; ++a2)
                #pragma unroll
                for (int a3 = 0; a3 < 2; ++a3)
                    acc[a0][a1][a2][a3] = (f32x4){0.f, 0.f, 0.f, 0.f};

    // prologue: slot0 <- kt0 complete (8 loads) + slot1 early half A1h0 <- kt1 (2 loads);
    // wait slot0 done (allow A1h0 in flight)
    STAGE_A(0, 0, 0); STAGE_A(0, 1, 0); STAGE_B(0, 0, 0); STAGE_B(0, 1, 0);
    STAGE_A(1, 0, 1);
    asm volatile("s_waitcnt vmcnt(2)" ::: "memory");
    __builtin_amdgcn_sched_barrier(0);
    __builtin_amdgcn_s_barrier();

    for (int it = 0; it < NI; ++it) {
        const int kt1 = 2 * it + 1, kt2 = 2 * it + 2, kt3 = 2 * it + 3;
        const bool nl = (it + 1 < NI);
        PHASE4(0, 0, TAIL_NONE, STAGE_A(1, 1, kt1); STAGE_B(1, 0, kt1); STAGE_B(1, 1, kt1));
        PHASE4(0, 1, TAIL_V2L,  if (nl) STAGE_A(0, 0, kt2));
        PHASE4(1, 0, TAIL_NONE, if (nl) { STAGE_A(0, 1, kt2); STAGE_B(0, 0, kt2); STAGE_B(0, 1, kt2); });
        PHASE4(1, 1, TAIL_V2N,  if (nl) STAGE_A(1, 0, kt3));
    }

    // epilogue: LDS quiescent (last-iter vmcnt(0) at end-Q2, no stages after).
    float* partf = (float*)&As[0][0][0];   // [8 waves][4 (lq*2+nj)][16 r16]
    float* wcs   = (float*)&Bs[0][0][0];   // [256] w_combine slice
    if (t < 256) wcs[t] = w_combine[(size_t)b * Cn + m0 + t];
    __syncthreads();

    // lane holds D[m = hq*128 + wr*64 + mi*16 + q4*4 + r][s = lq*128 + wc*32 + nj*16 + r16]
    #pragma unroll
    for (int lq = 0; lq < 2; ++lq)
        #pragma unroll
        for (int nj = 0; nj < 2; ++nj) {
            float s = 0.f;
            #pragma unroll
            for (int hq = 0; hq < 2; ++hq)
                #pragma unroll
                for (int mi = 0; mi < 4; ++mi)
                    #pragma unroll
                    for (int r = 0; r < 4; ++r)
                        s += tanhf(acc[hq][lq][mi][nj][r])
                             * wcs[hq * 128 + wr * 64 + mi * 16 + q4 * 4 + r];
            s += __shfl_xor(s, 16, 64);
            s += __shfl_xor(s, 32, 64);
            if (q4 == 0) partf[(wid * 4 + lq * 2 + nj) * 16 + r16] = s;
        }
    __syncthreads();
    if (t < 256) {
        const int lq = t >> 7, wcq = (t >> 5) & 3, nj = (t >> 4) & 1, rr = t & 15;
        const float tot = partf[(wcq * 4 + lq * 2 + nj) * 16 + rr]
                        + partf[((4 + wcq) * 4 + lq * 2 + nj) * 16 + rr];
        atomicAdd(&scores[(size_t)b * Sn + n0 + t], tot);
    }
}

__global__ __launch_bounds__(256)
void softmax_kernel(const float* __restrict__ scores, float* __restrict__ weight)
{
    __shared__ float red[4];
    const int b = blockIdx.x, t = threadIdx.x;
    const int lane = t & 63, wid = t >> 6;
    const float v0 = scores[(size_t)b * Sn + t];
    const float v1 = scores[(size_t)b * Sn + 256 + t];
    float m = fmaxf(v0, v1);
    #pragma unroll
    for (int off = 32; off >= 1; off >>= 1) m = fmaxf(m, __shfl_xor(m, off, 64));
    if (lane == 0) red[wid] = m;
    __syncthreads();
    const float M = fmaxf(fmaxf(red[0], red[1]), fmaxf(red[2], red[3]));
    __syncthreads();
    const float e0 = expf(v0 - M), e1 = expf(v1 - M);
    float s = e0 + e1;
    #pragma unroll
    for (int off = 32; off >= 1; off >>= 1) s += __shfl_xor(s, off, 64);
    if (lane == 0) red[wid] = s;
    __syncthreads();
    const float inv = 1.0f / (red[0] + red[1] + red[2] + red[3]);
    weight[(size_t)b * Sn + t]       = e0 * inv;
    weight[(size_t)b * Sn + 256 + t] = e1 * inv;
}

// out[b,h] = sum_s text[b,s,h] * weight[b,s]; one thread per h-column, no atomics
__global__ __launch_bounds__(256)
void out_kernel(const float* __restrict__ text, const float* __restrict__ weight,
                float* __restrict__ out)
{
    __shared__ float ws[Sn];
    const int b = blockIdx.y, hc = blockIdx.x;
    const int t = threadIdx.x;
    ws[t]       = weight[(size_t)b * Sn + t];
    ws[t + 256] = weight[(size_t)b * Sn + 256 + t];
    __syncthreads();
    const int h = hc * 256 + t;
    const float* tb = text + (size_t)b * Sn * Hn + h;
    float acc = 0.f;
    #pragma unroll 8
    for (int s = 0; s < Sn; ++s)
        acc += tb[(size_t)s * Hn] * ws[s];
    out[(size_t)b * Hn + h] = acc;
}

extern "C" void kernel_launch(void* const* d_in, const int* in_sizes, int n_in,
                              void* d_out, int out_size, void* d_ws, size_t ws_size,
                              hipStream_t stream)
{
    const float* text      = (const float*)d_in[0];
    const float* aspect    = (const float*)d_in[1];
    const float* w_text    = (const float*)d_in[2];
    const float* w_aspect  = (const float*)d_in[3];
    const float* w_combine = (const float*)d_in[4];

    float* outp   = (float*)d_out;
    float* weight = outp;                       // [B,S]
    float* outv   = outp + (size_t)Bn * Sn;     // [B,H]

    ushort_t* bf   = (ushort_t*)d_ws;           // 327 MB of bf16 segments
    float* scores  = (float*)((char*)d_ws + WS_BF_BYTES);   // [B,S] scratch

    const ushort_t* text_bf    = bf;
    const ushort_t* aspect_bf  = bf + T_TEXT;
    const ushort_t* wtext_bf   = bf + T_ASPECT;
    const ushort_t* waspect_bf = bf + T_WTEXT;

    hipMemsetAsync(scores, 0, (size_t)Bn * Sn * sizeof(float), stream);
    convert_kernel<<<2048, 256, 0, stream>>>(text, aspect, w_text, w_aspect, bf);
    scores_kernel<<<dim3(2, 7, Bn), 512, 0, stream>>>(text_bf, aspect_bf, wtext_bf, waspect_bf,
                                                      w_combine, scores);
    softmax_kernel<<<Bn, 256, 0, stream>>>(scores, weight);
    out_kernel<<<dim3(4, Bn), 256, 0, stream>>>(text, weight, outv);
}

// Round 8
// 852.514 us; speedup vs baseline: 1.0247x; 1.0247x over previous
//
#include <hip/hip_runtime.h>
#include <stdint.h>

#define Bn 64
#define Sn 512
#define Hn 1024
#define En 768
#define Cn (Hn + En)   // 1792

typedef __bf16 bf16_t;
typedef bf16_t bf16x8 __attribute__((ext_vector_type(8)));
typedef float  f32x4  __attribute__((ext_vector_type(4)));
typedef unsigned int uint32;
typedef uint32 u32x4 __attribute__((ext_vector_type(4)));
typedef unsigned short ushort_t;

// flat element offsets of the bf16 scratch segments (order: text, aspect, w_text, w_aspect)
#define T_TEXT   33554432u   // 64*512*1024
#define T_ASPECT 58720256u   // + 64*512*768
#define T_WTEXT  125829120u  // + 64*1024*1024
#define T_TOTAL  163577856u  // + 64*768*768
#define WS_BF_BYTES ((size_t)T_TOTAL * 2)

// fp32 -> bf16 (round-half-up), pack two into one dword
__device__ __forceinline__ uint32 pack2_bf16(float a, float b) {
    uint32 ua = __float_as_uint(a) + 0x8000u;
    uint32 ub = __float_as_uint(b) + 0x8000u;
    return (ub & 0xFFFF0000u) | (ua >> 16);
}

// R7 counters: grid-stride convert = 2.8 TB/s (35% peak) — per-iteration segment
// branch + interleaved store/load defeats pipelining. R8: flat one-shot, 16
// elements/thread (64B read, 32B write), block-uniform segment select (all
// segment bounds divisible by 4096-elem block quantum -> scalar branch).
__global__ __launch_bounds__(256)
void convert_kernel(const float* __restrict__ text, const float* __restrict__ aspect,
                    const float* __restrict__ w_text, const float* __restrict__ w_aspect,
                    ushort_t* __restrict__ dst)
{
    const size_t i = ((size_t)blockIdx.x * 256 + threadIdx.x) * 16;
    const float* src; size_t off;
    if (i < T_TEXT)        { src = text;     off = i; }
    else if (i < T_ASPECT) { src = aspect;   off = i - T_TEXT; }
    else if (i < T_WTEXT)  { src = w_text;   off = i - T_ASPECT; }
    else                   { src = w_aspect; off = i - T_WTEXT; }
    const f32x4* sp = (const f32x4*)(src + off);
    f32x4 a0 = sp[0], a1 = sp[1], a2 = sp[2], a3 = sp[3];
    u32x4 p0 = { pack2_bf16(a0.x, a0.y), pack2_bf16(a0.z, a0.w),
                 pack2_bf16(a1.x, a1.y), pack2_bf16(a1.z, a1.w) };
    u32x4 p1 = { pack2_bf16(a2.x, a2.y), pack2_bf16(a2.z, a2.w),
                 pack2_bf16(a3.x, a3.y), pack2_bf16(a3.z, a3.w) };
    u32x4* dp = (u32x4*)(dst + i);
    dp[0] = p0;
    dp[1] = p1;
}

// ---------------------------------------------------------------------------
// scores[b,s] = sum_c w_combine[b,c] * tanh( (W @ X^T)[c,s] )
// 256x256 tile, 8 waves (2Mx4N), BK=64, 4 fat phases per iter (2 K-tiles).
// R5 counters (8-phase): MfmaUtil 16%, 23k cyc/iter = 3.5x m201's per-iter cost.
// Diagnosis: per-phase sync overhead (16 barriers/iter, 8-wave lockstep,
// 1 block/CU) + 96 ds_read_b128/lane/iter. Fix: one phase per (slot, A-half)
// computing BOTH LQ quadrants (32 MFMA), sharing B-fragments across quadrants:
// barriers 16->8/iter, reads 96->64/lane/iter.  [R7: verified — scores dropped
// out of top-5 (<=233 us, was 271).]
//
// Phase plan per iter it (slot0 holds kt=2it, slot1 holds kt=2it+1):
//   Q1: slot0 HQ0 (reads A0h0 + B0 both)   stage A1h1,B1h0,B1h1 <- kt1
//   Q2: slot0 HQ1 (reads A0h1 + B0 both)   stage A0h0 <- kt2 (nl)   TAIL vmcnt(2)/(0)
//   Q3: slot1 HQ0 (reads A1h0 + B1 both)   stage A0h1,B0h0,B0h1 <- kt2 (nl)
//   Q4: slot1 HQ1 (reads A1h1 + B1 both)   stage A1h0 <- kt3 (nl)   TAIL vmcnt(2) (nl)
// Write-after-read (barrier-separated, audited): every staged half's last
// reader completed (lgkmcnt(0) before MFMA) >= one barrier before the stage.
// Counted waits: end-Q2 vmcnt(2) forces prevQ4's 2 + Q1's 6 (slot1 complete,
// cross-wave via the post-TAIL barrier) allowing Q2's pair in flight; end-Q4
// vmcnt(2) forces Q2's 2 + Q3's 6 (slot0 complete) allowing Q4's pair.
// Last iter: Q2 drains vmcnt(0); Q3/Q4 stage nothing -> LDS quiescent for the
// epilogue overlay.
// ---------------------------------------------------------------------------

#define STAGE_A(SLOT, H, KT) do {                                                       \
    const ushort_t* _g = Ag + (size_t)((H) * 128) * K + (size_t)(KT) * 64;              \
    __builtin_amdgcn_global_load_lds(                                                   \
        (const __attribute__((address_space(1))) void*)_g,                              \
        (__attribute__((address_space(3))) void*)&As[SLOT][(H) * 128 + wid * 8][0],     \
        16, 0, 0);                                                                      \
    __builtin_amdgcn_global_load_lds(                                                   \
        (const __attribute__((address_space(1))) void*)(_g + (size_t)64 * K),           \
        (__attribute__((address_space(3))) void*)&As[SLOT][(H) * 128 + 64 + wid * 8][0],\
        16, 0, 0);                                                                      \
} while (0)

#define STAGE_B(SLOT, H, KT) do {                                                       \
    const ushort_t* _g = Bg + (size_t)((H) * 128) * K + (size_t)(KT) * 64;              \
    __builtin_amdgcn_global_load_lds(                                                   \
        (const __attribute__((address_space(1))) void*)_g,                              \
        (__attribute__((address_space(3))) void*)&Bs[SLOT][(H) * 128 + wid * 8][0],     \
        16, 0, 0);                                                                      \
    __builtin_amdgcn_global_load_lds(                                                   \
        (const __attribute__((address_space(1))) void*)(_g + (size_t)64 * K),           \
        (__attribute__((address_space(3))) void*)&Bs[SLOT][(H) * 128 + 64 + wid * 8][0],\
        16, 0, 0);                                                                      \
} while (0)

#define TAIL_NONE
#define TAIL_V2L if (nl) { asm volatile("s_waitcnt vmcnt(2)" ::: "memory"); }           \
                 else    { asm volatile("s_waitcnt vmcnt(0)" ::: "memory"); }
#define TAIL_V2N if (nl) { asm volatile("s_waitcnt vmcnt(2)" ::: "memory"); }

// fat phase: 16 ds_read_b128 (A-half HQ + B both quadrants) + stages | barrier |
// lgkm0 | 32 MFMA (both LQ) | TAIL | barrier
#define PHASE4(SLOT, HQ, TAIL, ...) do {                                                \
    bf16x8 af[2][4], bv[2][2][2];                                                       \
    _Pragma("unroll")                                                                   \
    for (int ks = 0; ks < 2; ++ks) {                                                    \
        const int cc = ks ? c1 : c0;                                                    \
        _Pragma("unroll")                                                               \
        for (int mi = 0; mi < 4; ++mi)                                                  \
            af[ks][mi] = *(const bf16x8*)&As[SLOT][(HQ) * 128 + rowA0 + mi * 16][cc];   \
        _Pragma("unroll")                                                               \
        for (int lq = 0; lq < 2; ++lq)                                                  \
            _Pragma("unroll")                                                           \
            for (int nj = 0; nj < 2; ++nj)                                              \
                bv[lq][ks][nj] = *(const bf16x8*)&Bs[SLOT][lq * 128 + rowB0 + nj * 16][cc]; \
    }                                                                                   \
    __VA_ARGS__;                                                                        \
    __builtin_amdgcn_sched_barrier(0);                                                  \
    __builtin_amdgcn_s_barrier();                                                       \
    asm volatile("s_waitcnt lgkmcnt(0)" ::: "memory");                                  \
    __builtin_amdgcn_sched_barrier(0);                                                  \
    __builtin_amdgcn_s_setprio(1);                                                      \
    _Pragma("unroll")                                                                   \
    for (int ks = 0; ks < 2; ++ks)                                                      \
        _Pragma("unroll")                                                               \
        for (int lq = 0; lq < 2; ++lq)                                                  \
            _Pragma("unroll")                                                           \
            for (int mi = 0; mi < 4; ++mi)                                              \
                _Pragma("unroll")                                                       \
                for (int nj = 0; nj < 2; ++nj)                                          \
                    acc[HQ][lq][mi][nj] = __builtin_amdgcn_mfma_f32_16x16x32_bf16(      \
                        af[ks][mi], bv[lq][ks][nj], acc[HQ][lq][mi][nj], 0, 0, 0);      \
    __builtin_amdgcn_s_setprio(0);                                                      \
    TAIL                                                                                \
    __builtin_amdgcn_sched_barrier(0);                                                  \
    __builtin_amdgcn_s_barrier();                                                       \
} while (0)

__global__ __launch_bounds__(512, 2)
void scores_kernel(const ushort_t* __restrict__ text_bf,
                   const ushort_t* __restrict__ aspect_bf,
                   const ushort_t* __restrict__ wtext_bf,
                   const ushort_t* __restrict__ waspect_bf,
                   const float* __restrict__ w_combine,
                   float* __restrict__ scores)
{
    // LDS: 2 K-tile slots x [256 rows][64 cols] bf16 per matrix = 128 KiB total.
    // Row r's 8-element chunks stored at chunk c = global_chunk ^ (r&7) (bank-even b128).
    __shared__ __align__(16) ushort_t As[2][256][64];
    __shared__ __align__(16) ushort_t Bs[2][256][64];

    // bijective XCD swizzle: 896 = 8 XCD * 112; each XCD gets 8 contiguous batches
    const int lin = blockIdx.x + 2 * (blockIdx.y + 7 * blockIdx.z);
    const int wg  = (lin & 7) * 112 + (lin >> 3);
    const int bx = wg % 2;
    const int by = (wg / 2) % 7;
    const int b  = wg / 14;

    const int m0 = by * 256;            // channel tile base (0..1536)
    const int n0 = bx * 256;            // s tile base (0 or 256)
    const bool is_text = (m0 < Hn);
    const int K  = is_text ? Hn : En;   // 1024 or 768
    const int NI = K >> 7;              // iters (2 K-tiles of 64 per iter): 8 or 6
    const ushort_t* Amat = is_text ? (wtext_bf   + (size_t)b * Hn * Hn + (size_t)m0 * Hn)
                                   : (waspect_bf + (size_t)b * En * En + (size_t)(m0 - Hn) * En);
    const ushort_t* Bmat = is_text ? (text_bf   + (size_t)b * Sn * Hn + (size_t)n0 * Hn)
                                   : (aspect_bf + (size_t)b * Sn * En + (size_t)n0 * En);

    const int t = threadIdx.x;
    const int wid = t >> 6, lane = t & 63;
    const int r16 = lane & 15, q4 = lane >> 4;
    const int wr = wid >> 2, wc = wid & 3;       // wave grid 2(M) x 4(N)
    const int rowA0 = wr * 64 + r16;             // + HQ*128 + mi*16
    const int rowB0 = wc * 32 + r16;             // + LQ*128 + nj*16
    const int c0 = ((0 + q4) ^ (r16 & 7)) * 8;   // swizzled chunk col, ks=0 (elements)
    const int c1 = ((4 + q4) ^ (r16 & 7)) * 8;   // ks=1

    // staging: thread t covers sub-row t>>3 (of 64) / chunk t&7; global chunk pre-swizzled
    const int srow = t >> 3;
    const int cg = (t & 7) ^ (srow & 7);
    const ushort_t* Ag = Amat + (size_t)srow * K + (size_t)cg * 8;
    const ushort_t* Bg = Bmat + (size_t)srow * K + (size_t)cg * 8;

    f32x4 acc[2][2][4][2];   // [A-half][B-half][mi][nj]
    #pragma unroll
    for (int a0 = 0; a0 < 2; ++a0)
        #pragma unroll
        for (int a1 = 0; a1 < 2; ++a1)
            #pragma unroll
            for (int a2 = 0; a2 < 4; ++a2)
                #pragma unroll
                for (int a3 = 0; a3 < 2; ++a3)
                    acc[a0][a1][a2][a3] = (f32x4){0.f, 0.f, 0.f, 0.f};

    // prologue: slot0 <- kt0 complete (8 loads) + slot1 early half A1h0 <- kt1 (2 loads);
    // wait slot0 done (allow A1h0 in flight)
    STAGE_A(0, 0, 0); STAGE_A(0, 1, 0); STAGE_B(0, 0, 0); STAGE_B(0, 1, 0);
    STAGE_A(1, 0, 1);
    asm volatile("s_waitcnt vmcnt(2)" ::: "memory");
    __builtin_amdgcn_sched_barrier(0);
    __builtin_amdgcn_s_barrier();

    for (int it = 0; it < NI; ++it) {
        const int kt1 = 2 * it + 1, kt2 = 2 * it + 2, kt3 = 2 * it + 3;
        const bool nl = (it + 1 < NI);
        PHASE4(0, 0, TAIL_NONE, STAGE_A(1, 1, kt1); STAGE_B(1, 0, kt1); STAGE_B(1, 1, kt1));
        PHASE4(0, 1, TAIL_V2L,  if (nl) STAGE_A(0, 0, kt2));
        PHASE4(1, 0, TAIL_NONE, if (nl) { STAGE_A(0, 1, kt2); STAGE_B(0, 0, kt2); STAGE_B(0, 1, kt2); });
        PHASE4(1, 1, TAIL_V2N,  if (nl) STAGE_A(1, 0, kt3));
    }

    // epilogue: LDS quiescent (last-iter vmcnt(0) at end-Q2, no stages after).
    float* partf = (float*)&As[0][0][0];   // [8 waves][4 (lq*2+nj)][16 r16]
    float* wcs   = (float*)&Bs[0][0][0];   // [256] w_combine slice
    if (t < 256) wcs[t] = w_combine[(size_t)b * Cn + m0 + t];
    __syncthreads();

    // lane holds D[m = hq*128 + wr*64 + mi*16 + q4*4 + r][s = lq*128 + wc*32 + nj*16 + r16]
    #pragma unroll
    for (int lq = 0; lq < 2; ++lq)
        #pragma unroll
        for (int nj = 0; nj < 2; ++nj) {
            float s = 0.f;
            #pragma unroll
            for (int hq = 0; hq < 2; ++hq)
                #pragma unroll
                for (int mi = 0; mi < 4; ++mi)
                    #pragma unroll
                    for (int r = 0; r < 4; ++r)
                        s += tanhf(acc[hq][lq][mi][nj][r])
                             * wcs[hq * 128 + wr * 64 + mi * 16 + q4 * 4 + r];
            s += __shfl_xor(s, 16, 64);
            s += __shfl_xor(s, 32, 64);
            if (q4 == 0) partf[(wid * 4 + lq * 2 + nj) * 16 + r16] = s;
        }
    __syncthreads();
    if (t < 256) {
        const int lq = t >> 7, wcq = (t >> 5) & 3, nj = (t >> 4) & 1, rr = t & 15;
        const float tot = partf[(wcq * 4 + lq * 2 + nj) * 16 + rr]
                        + partf[((4 + wcq) * 4 + lq * 2 + nj) * 16 + rr];
        atomicAdd(&scores[(size_t)b * Sn + n0 + t], tot);
    }
}

__global__ __launch_bounds__(256)
void softmax_kernel(const float* __restrict__ scores, float* __restrict__ weight)
{
    __shared__ float red[4];
    const int b = blockIdx.x, t = threadIdx.x;
    const int lane = t & 63, wid = t >> 6;
    const float v0 = scores[(size_t)b * Sn + t];
    const float v1 = scores[(size_t)b * Sn + 256 + t];
    float m = fmaxf(v0, v1);
    #pragma unroll
    for (int off = 32; off >= 1; off >>= 1) m = fmaxf(m, __shfl_xor(m, off, 64));
    if (lane == 0) red[wid] = m;
    __syncthreads();
    const float M = fmaxf(fmaxf(red[0], red[1]), fmaxf(red[2], red[3]));
    __syncthreads();
    const float e0 = expf(v0 - M), e1 = expf(v1 - M);
    float s = e0 + e1;
    #pragma unroll
    for (int off = 32; off >= 1; off >>= 1) s += __shfl_xor(s, off, 64);
    if (lane == 0) red[wid] = s;
    __syncthreads();
    const float inv = 1.0f / (red[0] + red[1] + red[2] + red[3]);
    weight[(size_t)b * Sn + t]       = e0 * inv;
    weight[(size_t)b * Sn + 256 + t] = e1 * inv;
}

// out[b,h] = sum_s text[b,s,h] * weight[b,s]; one thread per h-column, no atomics
__global__ __launch_bounds__(256)
void out_kernel(const float* __restrict__ text, const float* __restrict__ weight,
                float* __restrict__ out)
{
    __shared__ float ws[Sn];
    const int b = blockIdx.y, hc = blockIdx.x;
    const int t = threadIdx.x;
    ws[t]       = weight[(size_t)b * Sn + t];
    ws[t + 256] = weight[(size_t)b * Sn + 256 + t];
    __syncthreads();
    const int h = hc * 256 + t;
    const float* tb = text + (size_t)b * Sn * Hn + h;
    float acc = 0.f;
    #pragma unroll 8
    for (int s = 0; s < Sn; ++s)
        acc += tb[(size_t)s * Hn] * ws[s];
    out[(size_t)b * Hn + h] = acc;
}

extern "C" void kernel_launch(void* const* d_in, const int* in_sizes, int n_in,
                              void* d_out, int out_size, void* d_ws, size_t ws_size,
                              hipStream_t stream)
{
    const float* text      = (const float*)d_in[0];
    const float* aspect    = (const float*)d_in[1];
    const float* w_text    = (const float*)d_in[2];
    const float* w_aspect  = (const float*)d_in[3];
    const float* w_combine = (const float*)d_in[4];

    float* outp   = (float*)d_out;
    float* weight = outp;                       // [B,S]
    float* outv   = outp + (size_t)Bn * Sn;     // [B,H]

    ushort_t* bf   = (ushort_t*)d_ws;           // 327 MB of bf16 segments
    float* scores  = (float*)((char*)d_ws + WS_BF_BYTES);   // [B,S] scratch

    const ushort_t* text_bf    = bf;
    const ushort_t* aspect_bf  = bf + T_TEXT;
    const ushort_t* wtext_bf   = bf + T_ASPECT;
    const ushort_t* waspect_bf = bf + T_WTEXT;

    hipMemsetAsync(scores, 0, (size_t)Bn * Sn * sizeof(float), stream);
    convert_kernel<<<T_TOTAL / 16 / 256, 256, 0, stream>>>(text, aspect, w_text, w_aspect, bf);
    scores_kernel<<<dim3(2, 7, Bn), 512, 0, stream>>>(text_bf, aspect_bf, wtext_bf, waspect_bf,
                                                      w_combine, scores);
    softmax_kernel<<<Bn, 256, 0, stream>>>(scores, weight);
    out_kernel<<<dim3(4, Bn), 256, 0, stream>>>(text, weight, outv);
}